// Round 1
// baseline (240.223 us; speedup 1.0000x reference)
//
#include <hip/hip_runtime.h>

#define VOL   2097152          // 128*128*128
#define TBL   4194304          // BATCH * VOL
#define D1D2  16384
#define DD2   128

typedef __bf16 bf16_t;
typedef bf16_t bf16x4 __attribute__((ext_vector_type(4)));
typedef bf16_t bf16x8 __attribute__((ext_vector_type(8)));
typedef float  floatx4 __attribute__((ext_vector_type(4)));

// ---------------- pre-kernels ----------------

__global__ void build_table_k(const int* __restrict__ idx, int* __restrict__ table, int n) {
    int t = blockIdx.x * blockDim.x + threadIdx.x;
    if (t < n) {
        int4 c = ((const int4*)idx)[t];                     // b, i0, i1, i2
        int p = ((c.x * 128 + c.y) * 128 + c.z) * 128 + c.w;
        table[p] = t;
    }
}

__global__ void cvt_feat_k(const float* __restrict__ f, bf16_t* __restrict__ fb, int n4) {
    int t = blockIdx.x * blockDim.x + threadIdx.x;
    if (t < n4) {
        float4 v = ((const float4*)f)[t];
        bf16x4 o = { (bf16_t)v.x, (bf16_t)v.y, (bf16_t)v.z, (bf16_t)v.w };
        ((bf16x4*)fb)[t] = o;
    }
}

// weight [co][27][ci] fp32  ->  wb [k][co][ci] bf16
__global__ void cvt_w_k(const float* __restrict__ w, bf16_t* __restrict__ wb) {
    int t = blockIdx.x * blockDim.x + threadIdx.x;
    if (t < 27 * 64 * 64) {
        int ci = t & 63;
        int co = (t >> 6) & 63;
        int k  = t >> 12;
        wb[t] = (bf16_t)w[(co * 27 + k) * 64 + ci];
    }
}

// ---------------- main conv kernel ----------------
// block = 256 thr (4 waves); tile = 64 voxels x 64 out-ch
// wave w: D tile m = co in [w*16, w*16+16), n = 64 voxels (4 groups of 16)
// mfma_f32_16x16x32_bf16: A[m=lane&15][k=quad*8+j], B[k=quad*8+j][n=lane&15],
//                         D col=lane&15, row=quad*4+reg   (m89/m91-verified)

__global__ __launch_bounds__(256) void conv_k(
        const bf16_t* __restrict__ fb, const bf16_t* __restrict__ wb,
        const int* __restrict__ table, const int* __restrict__ idx,
        const float* __restrict__ bias, float* __restrict__ out, int n)
{
    __shared__ int    s_packed[64];
    __shared__ bf16_t sF[64 * 72];   // gathered features, pad 64->72 (144 B stride)
    __shared__ bf16_t sW[64 * 72];   // W_k tile

    const int t    = threadIdx.x;
    const int tile = blockIdx.x * 64;

    if (t < 64) {
        int vn = tile + t;
        if (vn < n) {
            int4 c = ((const int4*)idx)[vn];
            s_packed[t] = ((c.x * 128 + c.y) * 128 + c.z) * 128 + c.w;
        } else {
            s_packed[t] = (int)0xC0000000;   // sentinel: all taps miss
        }
    }

    const int lane = t & 63;
    const int w    = t >> 6;        // wave id 0..3
    const int l15  = lane & 15;
    const int q    = lane >> 4;     // quad 0..3
    const int r    = t >> 2;        // staging row 0..63
    const int j    = t & 3;         // staging chunk 0..3 (16 ch each)

    floatx4 acc[4] = { {0,0,0,0}, {0,0,0,0}, {0,0,0,0}, {0,0,0,0} };

    __syncthreads();
    const int pk = s_packed[r];

    for (int k = 0; k < 27; ++k) {
        int k0 = k / 9, k1 = (k / 3) % 3, k2 = k % 3;
        int shift = (k0 - 1) * D1D2 + (k1 - 1) * DD2 + (k2 - 1);

        __syncthreads();   // previous iteration's LDS reads complete

        // ---- stage gathered features: row r, channels [j*16, j*16+16) ----
        int np  = pk + shift;
        int nbr = (np >= 0 && np < TBL) ? table[np] : -1;
        bf16x8 v0 = {}, v1 = {};
        if (nbr >= 0) {
            const bf16x8* src = (const bf16x8*)(fb + nbr * 64 + j * 16);
            v0 = src[0];
            v1 = src[1];
        }
        *(bf16x8*)&sF[r * 72 + j * 16]     = v0;
        *(bf16x8*)&sF[r * 72 + j * 16 + 8] = v1;

        // ---- stage W_k: row r=co, channels [j*16, j*16+16) ----
        {
            const bf16x8* wsrc = (const bf16x8*)(wb + (k * 64 + r) * 64 + j * 16);
            *(bf16x8*)&sW[r * 72 + j * 16]     = wsrc[0];
            *(bf16x8*)&sW[r * 72 + j * 16 + 8] = wsrc[1];
        }

        __syncthreads();

        // ---- 2 k-steps of 32, 4 voxel-groups each ----
        #pragma unroll
        for (int s = 0; s < 2; ++s) {
            bf16x8 a = *(const bf16x8*)&sW[(w * 16 + l15) * 72 + s * 32 + q * 8];
            #pragma unroll
            for (int g = 0; g < 4; ++g) {
                bf16x8 b = *(const bf16x8*)&sF[(g * 16 + l15) * 72 + s * 32 + q * 8];
                acc[g] = __builtin_amdgcn_mfma_f32_16x16x32_bf16(a, b, acc[g], 0, 0, 0);
            }
        }
    }

    // ---- epilogue: lane holds co = w*16 + q*4 + {0..3}, voxel = tile + g*16 + l15
    float4 bs = *(const float4*)&bias[w * 16 + q * 4];
    #pragma unroll
    for (int g = 0; g < 4; ++g) {
        int vn = tile + g * 16 + l15;
        if (vn < n) {
            float4 o;
            o.x = acc[g][0] + bs.x;
            o.y = acc[g][1] + bs.y;
            o.z = acc[g][2] + bs.z;
            o.w = acc[g][3] + bs.w;
            *(float4*)&out[vn * 64 + w * 16 + q * 4] = o;
        }
    }
}

// ---------------- launch ----------------

extern "C" void kernel_launch(void* const* d_in, const int* in_sizes, int n_in,
                              void* d_out, int out_size, void* d_ws, size_t ws_size,
                              hipStream_t stream) {
    const float* feat = (const float*)d_in[0];
    const float* wgt  = (const float*)d_in[1];
    const float* bias = (const float*)d_in[2];
    const int*   idx  = (const int*)d_in[3];
    float* out = (float*)d_out;

    const int n = in_sizes[0] / 64;          // active voxels

    // workspace layout: [table 16 MB][wbf 256 KB][fbf 33.5 MB]
    char* ws = (char*)d_ws;
    int*    table = (int*)ws;
    bf16_t* wbf   = (bf16_t*)(ws + (size_t)TBL * 4);
    bf16_t* fbf   = (bf16_t*)(ws + (size_t)TBL * 4 + 262144);

    hipMemsetAsync(table, 0xFF, (size_t)TBL * 4, stream);   // all -1
    build_table_k<<<(n + 255) / 256, 256, 0, stream>>>(idx, table, n);

    int n4 = n * 16;                                         // float4 groups
    cvt_feat_k<<<(n4 + 255) / 256, 256, 0, stream>>>(feat, fbf, n4);
    cvt_w_k<<<(27 * 4096 + 255) / 256, 256, 0, stream>>>(wgt, wbf);

    int blocks = (n + 63) / 64;
    conv_k<<<blocks, 256, 0, stream>>>(fbf, wbf, table, idx, bias, out, n);
}

// Round 5
// 238.967 us; speedup vs baseline: 1.0053x; 1.0053x over previous
//
#include <hip/hip_runtime.h>

#define VOL   2097152          // 128*128*128
#define TBL   4194304          // BATCH * VOL
#define D1D2  16384
#define DD2   128
#define TILE  128

typedef __bf16 bf16_t;
typedef bf16_t bf16x8 __attribute__((ext_vector_type(8)));
typedef float  floatx4 __attribute__((ext_vector_type(4)));

// ---------------- fused prep kernel ----------------
// block roles: [0, tblB) build table; [tblB, tblB+432) weight cvt;
//              [tblB+432, ...) feature cvt (original order).
// table must be memset to -1 before this dispatch (stream-ordered).

__global__ __launch_bounds__(256) void prep_k(const float* __restrict__ f,
                                              const float* __restrict__ w,
                                              const int* __restrict__ idx,
                                              int* __restrict__ table,
                                              bf16_t* __restrict__ wb,
                                              bf16_t* __restrict__ fb, int n) {
    const int b = blockIdx.x;
    const int tblB = (n + 255) >> 8;
    if (b < tblB) {
        int t = b * 256 + threadIdx.x;
        if (t < n) {
            int4 c = ((const int4*)idx)[t];                 // b, i0, i1, i2
            int p = ((c.x * 128 + c.y) * 128 + c.z) * 128 + c.w;
            table[p] = t;                                   // original voxel id
        }
    } else if (b < tblB + 432) {
        int t = (b - tblB) * 256 + threadIdx.x;
        if (t < 27 * 64 * 64) {                             // [co][27][ci] -> [k][co][ci]
            int ci = t & 63, co = (t >> 6) & 63, k = t >> 12;
            wb[t] = (bf16_t)w[(co * 27 + k) * 64 + ci];
        }
    } else {
        int t = (b - tblB - 432) * 256 + threadIdx.x;       // unit = (voxel, 8-ch)
        int pos = t >> 3, c = (t & 7) * 8;
        if (pos < n) {
            const float* src = f + (size_t)pos * 64 + c;
            float4 a  = *(const float4*)src;
            float4 b2 = *(const float4*)(src + 4);
            bf16x8 o = { (bf16_t)a.x,  (bf16_t)a.y,  (bf16_t)a.z,  (bf16_t)a.w,
                         (bf16_t)b2.x, (bf16_t)b2.y, (bf16_t)b2.z, (bf16_t)b2.w };
            *(bf16x8*)(fb + (size_t)pos * 64 + c) = o;
        }
    }
}

// ---------------- main conv kernel ----------------
// block = 256 thr (4 waves); tile = 128 voxels x 64 out-ch
// wave w: m = co in [w*16, w*16+16), n = 128 voxels (8 groups of 16)
// mfma_f32_16x16x32_bf16: D col=lane&15, row=quad*4+reg (m89/m91-verified)

__global__ __launch_bounds__(256) void conv_k(
        const bf16_t* __restrict__ fb, const bf16_t* __restrict__ wb,
        const int* __restrict__ table, const int* __restrict__ idx,
        const float* __restrict__ bias, float* __restrict__ out, int n)
{
    __shared__ int    s_pkd[TILE];
    __shared__ int    s_nbr[27 * TILE];   // original-id neighbor lookups
    __shared__ bf16_t sF[TILE * 72];      // gathered features (pad 64->72)
    __shared__ bf16_t sW[64 * 72];        // W_k tile

    const int t    = threadIdx.x;
    const int tile = blockIdx.x * TILE;

    if (t < TILE) {
        int vn = tile + t;
        if (vn < n) {
            int4 c = ((const int4*)idx)[vn];
            s_pkd[t] = ((c.x * 128 + c.y) * 128 + c.z) * 128 + c.w;
        } else {
            s_pkd[t] = (int)0xC0000000;   // sentinel: all taps miss
        }
    }
    __syncthreads();

    // precompute all 27*TILE neighbor lookups (independent, overlapped)
    for (int u = t; u < 27 * TILE; u += 256) {
        int k  = u >> 7;                  // TILE == 128
        int r  = u & (TILE - 1);
        int k0 = k / 9, k1 = (k / 3) % 3, k2 = k % 3;
        int np = s_pkd[r] + (k0 - 1) * D1D2 + (k1 - 1) * DD2 + (k2 - 1);
        s_nbr[u] = (np >= 0 && np < TBL) ? table[np] : -1;
    }

    const int lane = t & 63;
    const int w    = t >> 6;              // wave 0..3
    const int l15  = lane & 15;
    const int q    = lane >> 4;

    // staging roles: features 2 thr/row x 32 ch; weights 4 thr/row x 16 ch
    const int rF = t >> 1;                // feature row 0..127
    const int hF = t & 1;                 // half-row (32 ch = 4x bf16x8)
    const int rW = t >> 2;                // weight row (co) 0..63
    const int cW = t & 3;                 // 16-ch chunk (2x bf16x8!)

    floatx4 acc[8] = {};

    __syncthreads();                      // s_nbr ready

    // prefetch tap 0
    bf16x8 pf[4] = {{}, {}, {}, {}};
    bf16x8 pw0, pw1;
    {
        int nbr = s_nbr[rF];
        if (nbr >= 0) {
            const bf16x8* src = (const bf16x8*)(fb + (size_t)nbr * 64 + hF * 32);
            pf[0] = src[0];
            pf[1] = src[1];
            pf[2] = src[2];
            pf[3] = src[3];
        }
        const bf16x8* wsrc = (const bf16x8*)(wb + rW * 64 + cW * 16);
        pw0 = wsrc[0];
        pw1 = wsrc[1];
    }

    for (int k = 0; k < 27; ++k) {
        // commit prefetched tap k to LDS (features: 32 ch, weights: 16 ch)
        *(bf16x8*)&sF[rF * 72 + hF * 32]      = pf[0];
        *(bf16x8*)&sF[rF * 72 + hF * 32 + 8]  = pf[1];
        *(bf16x8*)&sF[rF * 72 + hF * 32 + 16] = pf[2];
        *(bf16x8*)&sF[rF * 72 + hF * 32 + 24] = pf[3];
        *(bf16x8*)&sW[rW * 72 + cW * 16]      = pw0;
        *(bf16x8*)&sW[rW * 72 + cW * 16 + 8]  = pw1;

        // issue tap k+1 loads (waited on at NEXT iteration's LDS write)
        if (k + 1 < 27) {
            int nbr = s_nbr[(k + 1) * TILE + rF];
            bf16x8 n0 = {}, n1 = {}, n2 = {}, n3 = {};
            if (nbr >= 0) {
                const bf16x8* src = (const bf16x8*)(fb + (size_t)nbr * 64 + hF * 32);
                n0 = src[0];
                n1 = src[1];
                n2 = src[2];
                n3 = src[3];
            }
            const bf16x8* wsrc = (const bf16x8*)(wb + ((k + 1) * 64 + rW) * 64 + cW * 16);
            pw0   = wsrc[0];
            pw1   = wsrc[1];
            pf[0] = n0;
            pf[1] = n1;
            pf[2] = n2;
            pf[3] = n3;
        }

        __syncthreads();                  // staging visible

        #pragma unroll
        for (int s = 0; s < 2; ++s) {
            bf16x8 a = *(const bf16x8*)&sW[(w * 16 + l15) * 72 + s * 32 + q * 8];
            #pragma unroll
            for (int g = 0; g < 8; ++g) {
                bf16x8 bfrag = *(const bf16x8*)&sF[(g * 16 + l15) * 72 + s * 32 + q * 8];
                acc[g] = __builtin_amdgcn_mfma_f32_16x16x32_bf16(a, bfrag, acc[g], 0, 0, 0);
            }
        }

        __syncthreads();                  // MFMA reads done before next write
    }

    // epilogue: lane holds co = w*16 + q*4 + {0..3}, voxel = tile + g*16 + l15
    float4 bs = *(const float4*)&bias[w * 16 + q * 4];
    #pragma unroll
    for (int g = 0; g < 8; ++g) {
        int vn = tile + g * 16 + l15;
        if (vn < n) {
            float4 o;
            o.x = acc[g][0] + bs.x;
            o.y = acc[g][1] + bs.y;
            o.z = acc[g][2] + bs.z;
            o.w = acc[g][3] + bs.w;
            *(float4*)&out[(size_t)vn * 64 + w * 16 + q * 4] = o;
        }
    }
}

// ---------------- launch ----------------

extern "C" void kernel_launch(void* const* d_in, const int* in_sizes, int n_in,
                              void* d_out, int out_size, void* d_ws, size_t ws_size,
                              hipStream_t stream) {
    const float* feat = (const float*)d_in[0];
    const float* wgt  = (const float*)d_in[1];
    const float* bias = (const float*)d_in[2];
    const int*   idx  = (const int*)d_in[3];
    float* out = (float*)d_out;

    const int n = in_sizes[0] / 64;          // active voxels

    // ws layout (round-1 proven, 50.6 MB): [table 16MB][wbf 256KB][fbf 33.5MB]
    char* ws = (char*)d_ws;
    int*    table = (int*)ws;
    bf16_t* wbf   = (bf16_t*)(ws + (size_t)TBL * 4);
    bf16_t* fbf   = (bf16_t*)(ws + (size_t)TBL * 4 + 262144);

    hipMemsetAsync(table, 0xFF, (size_t)TBL * 4, stream);   // all -1

    int tblB = (n + 255) >> 8;
    int fB   = (n * 8 + 255) >> 8;
    prep_k<<<tblB + 432 + fB, 256, 0, stream>>>(feat, wgt, idx, table, wbf, fbf, n);

    conv_k<<<(n + TILE - 1) / TILE, 256, 0, stream>>>(fbf, wbf, table, idx, bias, out, n);
}